// Round 1
// baseline (105.785 us; speedup 1.0000x reference)
//
#include <hip/hip_runtime.h>

#define HIDDEN 128

// clang native vectors so __builtin_nontemporal_load/store apply cleanly.
typedef float f4 __attribute__((ext_vector_type(4)));
typedef int   i4 __attribute__((ext_vector_type(4)));

// Kernel 1: per-node dual projection.
// 16 lanes cooperate on one node: lane l loads floats [4l..4l+3] and
// [64+4l..64+4l+3] (two contiguous dwordx4 sweeps over the 512 B row),
// dots against W_src / W_dst quads, 4-stage shuffle reduce over 16 lanes.
// x is read exactly once -> nontemporal, so the p table written here is
// not evicted from L2/L3 before kernel 2's random gathers.
__global__ __launch_bounds__(256) void node_proj_kernel(
        const float* __restrict__ x,
        const float* __restrict__ W,
        float2* __restrict__ p,
        int n_nodes) {
    const int lane = threadIdx.x & 15;
    const int node = (int)((blockIdx.x * (unsigned)blockDim.x + threadIdx.x) >> 4);
    if (node >= n_nodes) return;

    const f4* xb = (const f4*)(x + (size_t)node * HIDDEN);
    const f4 x0 = __builtin_nontemporal_load(xb + lane);        // bytes 0..255 of row
    const f4 x1 = __builtin_nontemporal_load(xb + 16 + lane);   // bytes 256..511

    const f4* Wb = (const f4*)W;          // 1 KB, L1-resident
    const f4 ws0 = Wb[lane];
    const f4 ws1 = Wb[16 + lane];
    const f4 wd0 = Wb[32 + lane];
    const f4 wd1 = Wb[48 + lane];

    float ps = x0.x*ws0.x + x0.y*ws0.y + x0.z*ws0.z + x0.w*ws0.w
             + x1.x*ws1.x + x1.y*ws1.y + x1.z*ws1.z + x1.w*ws1.w;
    float pd = x0.x*wd0.x + x0.y*wd0.y + x0.z*wd0.z + x0.w*wd0.w
             + x1.x*wd1.x + x1.y*wd1.y + x1.z*wd1.z + x1.w*wd1.w;

    #pragma unroll
    for (int off = 8; off > 0; off >>= 1) {
        ps += __shfl_down(ps, off, 16);
        pd += __shfl_down(pd, off, 16);
    }
    if (lane == 0) p[node] = make_float2(ps, pd);
}

// Kernel 2: per-edge gather-add. 8 edges per thread: two int4 index loads
// per side (nontemporal, read-once), 16 independent 4 B gathers in flight
// (explicit float* indexing to guarantee dword loads, cached: p is
// L2/L3-resident), nontemporal float4x2 output store (write-once).
__global__ __launch_bounds__(256) void edge_out_kernel(
        const int* __restrict__ src,
        const int* __restrict__ dst,
        const float2* __restrict__ p,
        const float* __restrict__ b,
        float* __restrict__ out,
        int n_edges) {
    const int base = (int)(blockIdx.x * (unsigned)blockDim.x + threadIdx.x) * 8;
    if (base >= n_edges) return;
    const float bb = b[0];
    const float* pf = (const float*)p;   // pf[2i] = p_src(i), pf[2i+1] = p_dst(i)

    if (base + 7 < n_edges) {
        const i4 s0 = __builtin_nontemporal_load((const i4*)(src + base));
        const i4 s1 = __builtin_nontemporal_load((const i4*)(src + base) + 1);
        const i4 d0 = __builtin_nontemporal_load((const i4*)(dst + base));
        const i4 d1 = __builtin_nontemporal_load((const i4*)(dst + base) + 1);

        f4 o0, o1;
        o0.x = pf[2*s0.x] + pf[2*d0.x + 1] + bb;
        o0.y = pf[2*s0.y] + pf[2*d0.y + 1] + bb;
        o0.z = pf[2*s0.z] + pf[2*d0.z + 1] + bb;
        o0.w = pf[2*s0.w] + pf[2*d0.w + 1] + bb;
        o1.x = pf[2*s1.x] + pf[2*d1.x + 1] + bb;
        o1.y = pf[2*s1.y] + pf[2*d1.y + 1] + bb;
        o1.z = pf[2*s1.z] + pf[2*d1.z + 1] + bb;
        o1.w = pf[2*s1.w] + pf[2*d1.w + 1] + bb;

        __builtin_nontemporal_store(o0, (f4*)(out + base));
        __builtin_nontemporal_store(o1, (f4*)(out + base) + 1);
    } else {
        for (int e = base; e < n_edges; ++e)
            out[e] = pf[2*src[e]] + pf[2*dst[e] + 1] + bb;
    }
}

extern "C" void kernel_launch(void* const* d_in, const int* in_sizes, int n_in,
                              void* d_out, int out_size, void* d_ws, size_t ws_size,
                              hipStream_t stream) {
    const float* x   = (const float*)d_in[0];   // (n_nodes, 128) fp32
    const int*   ei  = (const int*)d_in[1];     // (2, n_edges) int32
    const float* W   = (const float*)d_in[2];   // (1, 256) fp32
    const float* b   = (const float*)d_in[3];   // (1,) fp32
    float* out = (float*)d_out;                 // (n_edges,) fp32

    const int n_nodes = in_sizes[0] / HIDDEN;
    const int n_edges = in_sizes[1] / 2;
    const int* src = ei;
    const int* dst = ei + n_edges;

    float2* p = (float2*)d_ws;  // n_nodes * 8 bytes = 800 KB

    // Kernel 1: 16 lanes/node, 16 nodes per 256-thread block.
    {
        const int nodes_per_block = 256 / 16;
        const int grid = (n_nodes + nodes_per_block - 1) / nodes_per_block;
        node_proj_kernel<<<grid, 256, 0, stream>>>(x, W, p, n_nodes);
    }

    // Kernel 2: 8 edges/thread.
    {
        const int threads = (n_edges + 7) / 8;
        const int grid = (threads + 255) / 256;
        edge_out_kernel<<<grid, 256, 0, stream>>>(src, dst, p, b, out, n_edges);
    }
}

// Round 3
// 98.786 us; speedup vs baseline: 1.0709x; 1.0709x over previous
//
#include <hip/hip_runtime.h>

#define HIDDEN 128

typedef float f4 __attribute__((ext_vector_type(4)));
typedef int   i4 __attribute__((ext_vector_type(4)));

// Kernel 1: per-node dual projection (round-0 structure: 32 lanes/node).
// Lane i loads x[node*128 + 4i..4i+3] (float4, wave = 2 nodes = 1 KB
// contiguous), dots against W_src / W_dst quads, then an interleaved
// xor-reduce: stage 1 pairs lanes so even lanes carry ps-sums and odd
// lanes carry pd-sums; stages 2..16 reduce both in one tree.
// 6 cross-lane ops per thread instead of 10.
__global__ __launch_bounds__(256) void node_proj_kernel(
        const float* __restrict__ x,
        const float* __restrict__ W,
        float* __restrict__ pf,          // 2*n_nodes floats: [ps0, pd0, ps1, pd1, ...]
        int n_nodes) {
    const int lane = threadIdx.x & 31;
    const int node = (int)((blockIdx.x * (unsigned)blockDim.x + threadIdx.x) >> 5);
    if (node >= n_nodes) return;

    const float4 xv = *(const float4*)(x + (size_t)node * HIDDEN + lane * 4);
    const float4 ws = *(const float4*)(W + lane * 4);
    const float4 wd = *(const float4*)(W + HIDDEN + lane * 4);

    float ps = xv.x * ws.x + xv.y * ws.y + xv.z * ws.z + xv.w * ws.w;
    float pd = xv.x * wd.x + xv.y * wd.y + xv.z * wd.z + xv.w * wd.w;

    // Stage 1: pairwise sums, parity-selected. Both shuffles execute on all
    // lanes (no divergence); the select is a v_cndmask.
    const float s2 = ps + __shfl_xor(ps, 1, 32);
    const float d2 = pd + __shfl_xor(pd, 1, 32);
    float v = (lane & 1) ? d2 : s2;

    // Stages 2,4,8,16: even lanes accumulate sum(ps), odd lanes sum(pd).
    #pragma unroll
    for (int off = 2; off < 32; off <<= 1)
        v += __shfl_xor(v, off, 32);

    // lane 0 -> pf[2*node] (ps), lane 1 -> pf[2*node+1] (pd): adjacent dwords.
    if (lane < 2) pf[2 * node + lane] = v;
}

// Kernel 2: per-edge gather-add (round-0 structure: 4 edges/thread,
// 3 waves/SIMD for latency hiding). NT on the read-once index streams and
// the write-once output so the 800 KB p table stays L2-resident for the
// random gathers.
__global__ __launch_bounds__(256) void edge_out_kernel(
        const int* __restrict__ src,
        const int* __restrict__ dst,
        const float* __restrict__ pf,    // pf[2i] = p_src(i), pf[2i+1] = p_dst(i)
        const float* __restrict__ b,
        float* __restrict__ out,
        int n_edges) {
    const int base = (int)(blockIdx.x * (unsigned)blockDim.x + threadIdx.x) * 4;
    if (base >= n_edges) return;
    const float bb = b[0];

    if (base + 3 < n_edges) {
        const i4 s = __builtin_nontemporal_load((const i4*)(src + base));
        const i4 d = __builtin_nontemporal_load((const i4*)(dst + base));
        f4 o;
        o.x = pf[2 * s.x] + pf[2 * d.x + 1] + bb;
        o.y = pf[2 * s.y] + pf[2 * d.y + 1] + bb;
        o.z = pf[2 * s.z] + pf[2 * d.z + 1] + bb;
        o.w = pf[2 * s.w] + pf[2 * d.w + 1] + bb;
        __builtin_nontemporal_store(o, (f4*)(out + base));
    } else {
        for (int e = base; e < n_edges; ++e)
            out[e] = pf[2 * src[e]] + pf[2 * dst[e] + 1] + bb;
    }
}

extern "C" void kernel_launch(void* const* d_in, const int* in_sizes, int n_in,
                              void* d_out, int out_size, void* d_ws, size_t ws_size,
                              hipStream_t stream) {
    const float* x   = (const float*)d_in[0];   // (n_nodes, 128) fp32
    const int*   ei  = (const int*)d_in[1];     // (2, n_edges) int32
    const float* W   = (const float*)d_in[2];   // (1, 256) fp32
    const float* b   = (const float*)d_in[3];   // (1,) fp32
    float* out = (float*)d_out;                 // (n_edges,) fp32

    const int n_nodes = in_sizes[0] / HIDDEN;
    const int n_edges = in_sizes[1] / 2;
    const int* src = ei;
    const int* dst = ei + n_edges;

    float* pf = (float*)d_ws;  // 2*n_nodes floats = 800 KB

    // Kernel 1: 32 lanes/node, 8 nodes per 256-thread block.
    {
        const int nodes_per_block = 256 / 32;
        const int grid = (n_nodes + nodes_per_block - 1) / nodes_per_block;
        node_proj_kernel<<<grid, 256, 0, stream>>>(x, W, pf, n_nodes);
    }

    // Kernel 2: 4 edges/thread.
    {
        const int threads = (n_edges + 3) / 4;
        const int grid = (threads + 255) / 256;
        edge_out_kernel<<<grid, 256, 0, stream>>>(src, dst, pf, b, out, n_edges);
    }
}